// Round 9
// baseline (305.479 us; speedup 1.0000x reference)
//
#include <hip/hip_runtime.h>
#include <math.h>

#define D_DIM 256
#define H_DIM 128
#define TILE  32
#define HPAD  264   // shorts per row: 528 B stride, 16B-aligned rows

typedef __attribute__((ext_vector_type(8))) short bf16x8;
typedef __attribute__((ext_vector_type(4))) float f32x4;

__device__ __forceinline__ unsigned short f32_to_bf16(float f) {
  unsigned int u = __float_as_uint(f);
  u += 0x7FFFu + ((u >> 16) & 1u);          // RTNE (setup kernel only)
  return (unsigned short)(u >> 16);
}

// two f32 -> packed bf16 pair (round-half-up); MFMA-input only
__device__ __forceinline__ unsigned int pack2_rn(float f0, float f1) {
  unsigned int u0 = (__float_as_uint(f0) + 0x8000u) & 0xFFFF0000u;
  unsigned int u1 = (__float_as_uint(f1) + 0x8000u) & 0xFFFF0000u;
  return (u0 >> 16) | u1;
}

__device__ __forceinline__ float tanh_fast(float x) {
  float e = __expf(2.0f * x);
  return 1.0f - 2.0f / (e + 1.0f);
}

// ---------------------------------------------------------------------------
// Setup: pre-swizzle W1 into per-lane bf16 B-fragments.
// Fragment f = kt*2+nt of thread t (lane l=t&63, wave w=t>>6):
//   elem j = W1[kt*32 + (l>>4)*8 + j][w*32 + nt*16 + (l&15)]
// ---------------------------------------------------------------------------
__global__ void setup_w1_kernel(const float* __restrict__ W1,
                                unsigned short* __restrict__ wfrag)
{
  const int t = threadIdx.x;
  const int l = t & 63, w = t >> 6;
  const int q = l >> 4, c = l & 15;
#pragma unroll
  for (int kt = 0; kt < 8; ++kt)
#pragma unroll
    for (int nt = 0; nt < 2; ++nt) {
      int f = kt * 2 + nt;
      int col = w * 32 + nt * 16 + c;
#pragma unroll
      for (int j = 0; j < 8; ++j) {
        int k = kt * 32 + q * 8 + j;
        wfrag[((size_t)f * 256 + t) * 8 + j] = f32_to_bf16(W1[k * H_DIM + col]);
      }
    }
}

// ---------------------------------------------------------------------------
// Segment start offsets (batch sorted; int32/int64 runtime detect).
// ---------------------------------------------------------------------------
__global__ void offsets_kernel(const void* __restrict__ batch, int* __restrict__ start,
                               int N, int G)
{
  int g = blockIdx.x * blockDim.x + threadIdx.x;
  if (g > G) return;
  const int* b32 = (const int*)batch;
  bool is64 = (b32[N - 1] != G - 1);
  int lo = 0, hi = N;
  while (lo < hi) {
    int mid = (lo + hi) >> 1;
    long long v = is64 ? ((const long long*)batch)[mid] : (long long)b32[mid];
    if (v < (long long)g) lo = mid + 1; else hi = mid;
  }
  start[g] = lo;
}

// ---------------------------------------------------------------------------
// Fused single-pass, block per graph, 32-node tiles (R8 schedule).
//  - thread owns rows srow+{0,8,16,24} x dims [scol8,scol8+8) as f32 in
//    NAMED registers A0..B3; pool reads these (zero LDS traffic, exact f32)
//  - LDS holds bf16-hi only (MFMA A operand)
//  - next tile double-buffered in N0..M3, loads issued at loop top
//  - amdgpu_waves_per_eu(3,3): pins the occupancy TARGET to 3 waves/EU so the
//    allocator may use up to 168 VGPR. launch_bounds(256,3) alone only sets
//    the MIN (=VGPR ceiling); the scheduler still chased 6 waves/EU -> 84
//    VGPR -> 180 MB/dispatch scratch spill (R4/R6/R8 signature).
// ---------------------------------------------------------------------------
__global__ __launch_bounds__(256)
__attribute__((amdgpu_waves_per_eu(3, 3)))
void fused_kernel(const float* __restrict__ x, const unsigned short* __restrict__ wfrag,
                  const float* __restrict__ b1, const float* __restrict__ W2,
                  const int* __restrict__ start, float* __restrict__ out, int N)
{
  __shared__ unsigned short xhi[TILE][HPAD];  // 16.9 KB
  __shared__ float part_t[TILE][4];           // logit partials (transposed)
  __shared__ float pacc_lds[8][D_DIM];        // 8 KB, end-of-block reduce only

  const int g = blockIdx.x;
  const int tid = threadIdx.x;
  const int s = start[g], e = start[g + 1];
  if (s >= e) { out[(size_t)g * D_DIM + tid] = 0.0f; return; }
  const int len = e - s;

  const int lane = tid & 63, w = tid >> 6;
  const int q = lane >> 4, c = lane & 15;
  const int srow = tid >> 5;              // 0..7: this thread's base row
  const int scol8 = (tid & 31) * 8;       // this thread's 8 dims

  const bf16x8* wfv = (const bf16x8*)wfrag;

  float b1c0, b1c1, w2c0, w2c1;
  {
    int col0 = w * 32 + c, col1 = w * 32 + 16 + c;
    b1c0 = b1[col0]; b1c1 = b1[col1];
    w2c0 = W2[col0]; w2c1 = W2[col1];
  }

  float m_run = -INFINITY, Z = 0.0f;
  float pc0 = 0.f, pc1 = 0.f, pc2 = 0.f, pc3 = 0.f,
        pc4 = 0.f, pc5 = 0.f, pc6 = 0.f, pc7 = 0.f;

  // ---- prologue: load tile 0 into named registers ----
  float4 A0, B0, A1, B1, A2, B2, A3, B3;
  {
    const float4* p0 = reinterpret_cast<const float4*>(x + (size_t)min(s + srow,      N - 1) * D_DIM + scol8);
    const float4* p1 = reinterpret_cast<const float4*>(x + (size_t)min(s + srow +  8, N - 1) * D_DIM + scol8);
    const float4* p2 = reinterpret_cast<const float4*>(x + (size_t)min(s + srow + 16, N - 1) * D_DIM + scol8);
    const float4* p3 = reinterpret_cast<const float4*>(x + (size_t)min(s + srow + 24, N - 1) * D_DIM + scol8);
    A0 = p0[0]; B0 = p0[1];
    A1 = p1[0]; B1 = p1[1];
    A2 = p2[0]; B2 = p2[1];
    A3 = p3[0]; B3 = p3[1];
  }

  const int nT = (len + TILE - 1) / TILE;
  for (int ti = 0; ti < nT; ++ti) {
    const int iend = min(TILE, len - ti * TILE);

    // ---- issue next tile's loads FIRST (hidden under this whole tile) ----
    float4 N0, M0, N1, M1, N2, M2, N3, M3;
    {
      const int nb = s + (ti + 1) * TILE;
      const float4* p0 = reinterpret_cast<const float4*>(x + (size_t)min(nb + srow,      N - 1) * D_DIM + scol8);
      const float4* p1 = reinterpret_cast<const float4*>(x + (size_t)min(nb + srow +  8, N - 1) * D_DIM + scol8);
      const float4* p2 = reinterpret_cast<const float4*>(x + (size_t)min(nb + srow + 16, N - 1) * D_DIM + scol8);
      const float4* p3 = reinterpret_cast<const float4*>(x + (size_t)min(nb + srow + 24, N - 1) * D_DIM + scol8);
      N0 = p0[0]; M0 = p0[1];
      N1 = p1[0]; M1 = p1[1];
      N2 = p2[0]; M2 = p2[1];
      N3 = p3[0]; M3 = p3[1];
    }

    // ---- stage bf16-hi of current tile (A regs) to LDS ----
    {
      uint4 H;
      H.x = pack2_rn(A0.x, A0.y); H.y = pack2_rn(A0.z, A0.w);
      H.z = pack2_rn(B0.x, B0.y); H.w = pack2_rn(B0.z, B0.w);
      *reinterpret_cast<uint4*>(&xhi[srow][scol8]) = H;
      H.x = pack2_rn(A1.x, A1.y); H.y = pack2_rn(A1.z, A1.w);
      H.z = pack2_rn(B1.x, B1.y); H.w = pack2_rn(B1.z, B1.w);
      *reinterpret_cast<uint4*>(&xhi[srow + 8][scol8]) = H;
      H.x = pack2_rn(A2.x, A2.y); H.y = pack2_rn(A2.z, A2.w);
      H.z = pack2_rn(B2.x, B2.y); H.w = pack2_rn(B2.z, B2.w);
      *reinterpret_cast<uint4*>(&xhi[srow + 16][scol8]) = H;
      H.x = pack2_rn(A3.x, A3.y); H.y = pack2_rn(A3.z, A3.w);
      H.z = pack2_rn(B3.x, B3.y); H.w = pack2_rn(B3.z, B3.w);
      *reinterpret_cast<uint4*>(&xhi[srow + 24][scol8]) = H;
    }
    __syncthreads();   // xhi ready

    // ---- MFMA (hi only): h = x_tile @ W1[:, wave's 32 cols] ----
    f32x4 acc00 = {0.f, 0.f, 0.f, 0.f}, acc01 = {0.f, 0.f, 0.f, 0.f};
    f32x4 acc10 = {0.f, 0.f, 0.f, 0.f}, acc11 = {0.f, 0.f, 0.f, 0.f};
#pragma unroll
    for (int kt = 0; kt < 8; ++kt) {
      const int koff = kt * 32 + q * 8;
      bf16x8 ah0 = *reinterpret_cast<const bf16x8*>(&xhi[c][koff]);
      bf16x8 ah1 = *reinterpret_cast<const bf16x8*>(&xhi[16 + c][koff]);
      bf16x8 bf0 = wfv[(kt * 2 + 0) * 256 + tid];   // L2-resident
      bf16x8 bf1 = wfv[(kt * 2 + 1) * 256 + tid];
      acc00 = __builtin_amdgcn_mfma_f32_16x16x32_bf16(ah0, bf0, acc00, 0, 0, 0);
      acc01 = __builtin_amdgcn_mfma_f32_16x16x32_bf16(ah0, bf1, acc01, 0, 0, 0);
      acc10 = __builtin_amdgcn_mfma_f32_16x16x32_bf16(ah1, bf0, acc10, 0, 0, 0);
      acc11 = __builtin_amdgcn_mfma_f32_16x16x32_bf16(ah1, bf1, acc11, 0, 0, 0);
    }

    // ---- tanh + W2 dot; reduce across the 16 col-lanes -> part_t[row][w] ----
#pragma unroll
    for (int r = 0; r < 4; ++r) {
      float v = tanh_fast(acc00[r] + b1c0) * w2c0 + tanh_fast(acc01[r] + b1c1) * w2c1;
#pragma unroll
      for (int o = 1; o < 16; o <<= 1) v += __shfl_xor(v, o, 64);
      if (c == 0) part_t[q * 4 + r][w] = v;
    }
#pragma unroll
    for (int r = 0; r < 4; ++r) {
      float v = tanh_fast(acc10[r] + b1c0) * w2c0 + tanh_fast(acc11[r] + b1c1) * w2c1;
#pragma unroll
      for (int o = 1; o < 16; o <<= 1) v += __shfl_xor(v, o, 64);
      if (c == 0) part_t[16 + q * 4 + r][w] = v;
    }
    __syncthreads();   // part ready (also: all frag reads done)

    // ---- online softmax, redundant in every wave (lane i&31 owns e_i) ----
    {
      const int i = lane & 31;
      float4 pp = *reinterpret_cast<const float4*>(&part_t[i][0]);
      float li = (i < iend) ? (pp.x + pp.y + pp.z + pp.w) : -INFINITY;
      float tmax = li;
#pragma unroll
      for (int o = 1; o < 32; o <<= 1) tmax = fmaxf(tmax, __shfl_xor(tmax, o, 64));
      float m_new = fmaxf(m_run, tmax);
      float ei = __expf(li - m_new);              // 0 for pad lanes
      float esum = ei;
#pragma unroll
      for (int o = 1; o < 32; o <<= 1) esum += __shfl_xor(esum, o, 64);
      float scale = __expf(m_run - m_new);        // first tile: exp(-inf)=0
      Z = Z * scale + esum;
      m_run = m_new;

      // ---- pool from REGISTERS (exact f32; zero LDS traffic) ----
      float e0 = __shfl(ei, srow,      64);
      float e1 = __shfl(ei, srow +  8, 64);
      float e2 = __shfl(ei, srow + 16, 64);
      float e3 = __shfl(ei, srow + 24, 64);
      pc0 *= scale; pc1 *= scale; pc2 *= scale; pc3 *= scale;
      pc4 *= scale; pc5 *= scale; pc6 *= scale; pc7 *= scale;
      pc0 = fmaf(e0, A0.x, pc0); pc1 = fmaf(e0, A0.y, pc1);
      pc2 = fmaf(e0, A0.z, pc2); pc3 = fmaf(e0, A0.w, pc3);
      pc4 = fmaf(e0, B0.x, pc4); pc5 = fmaf(e0, B0.y, pc5);
      pc6 = fmaf(e0, B0.z, pc6); pc7 = fmaf(e0, B0.w, pc7);
      pc0 = fmaf(e1, A1.x, pc0); pc1 = fmaf(e1, A1.y, pc1);
      pc2 = fmaf(e1, A1.z, pc2); pc3 = fmaf(e1, A1.w, pc3);
      pc4 = fmaf(e1, B1.x, pc4); pc5 = fmaf(e1, B1.y, pc5);
      pc6 = fmaf(e1, B1.z, pc6); pc7 = fmaf(e1, B1.w, pc7);
      pc0 = fmaf(e2, A2.x, pc0); pc1 = fmaf(e2, A2.y, pc1);
      pc2 = fmaf(e2, A2.z, pc2); pc3 = fmaf(e2, A2.w, pc3);
      pc4 = fmaf(e2, B2.x, pc4); pc5 = fmaf(e2, B2.y, pc5);
      pc6 = fmaf(e2, B2.z, pc6); pc7 = fmaf(e2, B2.w, pc7);
      pc0 = fmaf(e3, A3.x, pc0); pc1 = fmaf(e3, A3.y, pc1);
      pc2 = fmaf(e3, A3.z, pc2); pc3 = fmaf(e3, A3.w, pc3);
      pc4 = fmaf(e3, B3.x, pc4); pc5 = fmaf(e3, B3.y, pc5);
      pc6 = fmaf(e3, B3.z, pc6); pc7 = fmaf(e3, B3.w, pc7);
    }

    // ---- rotate: next tile's registers become current ----
    A0 = N0; B0 = M0;
    A1 = N1; B1 = M1;
    A2 = N2; B2 = M2;
    A3 = N3; B3 = M3;
  }

  // ---- cross-thread reduce of pooled partials ----
  *reinterpret_cast<float4*>(&pacc_lds[srow][scol8])     = make_float4(pc0, pc1, pc2, pc3);
  *reinterpret_cast<float4*>(&pacc_lds[srow][scol8 + 4]) = make_float4(pc4, pc5, pc6, pc7);
  __syncthreads();
  float sum = 0.f;
#pragma unroll
  for (int r = 0; r < 8; ++r) sum += pacc_lds[r][tid];
  out[(size_t)g * D_DIM + tid] = sum / Z;
}

// ---------------------------------------------------------------------------
extern "C" void kernel_launch(void* const* d_in, const int* in_sizes, int n_in,
                              void* d_out, int out_size, void* d_ws, size_t ws_size,
                              hipStream_t stream)
{
  const float* x     = (const float*)d_in[0];
  const void*  batch = d_in[1];
  const float* W1    = (const float*)d_in[2];
  const float* b1    = (const float*)d_in[3];
  const float* W2    = (const float*)d_in[4];
  // d_in[5] = b2: cancels exactly in the segment softmax -> unused.

  const int N = in_sizes[0] / D_DIM;     // 500000
  const int G = out_size / D_DIM;        // 4096

  unsigned short* wfrag = (unsigned short*)d_ws;              // 64 KB
  int* startA = (int*)((char*)d_ws + 16 * 256 * 8 * sizeof(unsigned short));
  float* out = (float*)d_out;

  setup_w1_kernel<<<1, 256, 0, stream>>>(W1, wfrag);
  offsets_kernel<<<(G + 1 + 255) / 256, 256, 0, stream>>>(batch, startA, N, G);
  fused_kernel<<<G, 256, 0, stream>>>(x, wfrag, b1, W2, startA, out, N);
}

// Round 10
// 222.371 us; speedup vs baseline: 1.3737x; 1.3737x over previous
//
#include <hip/hip_runtime.h>
#include <math.h>

#define D_DIM 256
#define H_DIM 128
#define TILE  32
#define HPAD  264   // shorts per LDS row: stride 528 B -> 2-way max aliasing (free)

typedef __attribute__((ext_vector_type(8))) short bf16x8;
typedef __attribute__((ext_vector_type(4))) float f32x4;

__device__ __forceinline__ unsigned short f32_to_bf16(float f) {
  unsigned int u = __float_as_uint(f);
  u += 0x7FFFu + ((u >> 16) & 1u);          // RTNE (setup kernel only)
  return (unsigned short)(u >> 16);
}

// hi = round-half-up bf16; lo = exact residual (f == hi + lo in f32).
// MFMA uses hi only (rel err <= 2^-9); pool reconstructs hi+lo exactly.
__device__ __forceinline__ unsigned int pack_hi2(float f0, float f1, float& r0, float& r1) {
  unsigned int u0 = (__float_as_uint(f0) + 0x8000u) & 0xFFFF0000u;
  unsigned int u1 = (__float_as_uint(f1) + 0x8000u) & 0xFFFF0000u;
  r0 = f0 - __uint_as_float(u0);
  r1 = f1 - __uint_as_float(u1);
  return (u0 >> 16) | u1;
}
__device__ __forceinline__ unsigned int pack_lo2(float r0, float r1) {
  return (__float_as_uint(r0) >> 16) | (__float_as_uint(r1) & 0xFFFF0000u);
}

__device__ __forceinline__ float tanh_fast(float x) {
  float e = __expf(2.0f * x);
  return 1.0f - 2.0f / (e + 1.0f);
}

// ---------------------------------------------------------------------------
// Setup: pre-swizzle W1 into per-lane bf16 B-fragments (see R2 comment).
// ---------------------------------------------------------------------------
__global__ void setup_w1_kernel(const float* __restrict__ W1,
                                unsigned short* __restrict__ wfrag)
{
  const int t = threadIdx.x;
  const int l = t & 63, w = t >> 6;
  const int q = l >> 4, c = l & 15;
#pragma unroll
  for (int kt = 0; kt < 8; ++kt)
#pragma unroll
    for (int nt = 0; nt < 2; ++nt) {
      int f = kt * 2 + nt;
      int col = w * 32 + nt * 16 + c;
#pragma unroll
      for (int j = 0; j < 8; ++j) {
        int k = kt * 32 + q * 8 + j;
        wfrag[((size_t)f * 256 + t) * 8 + j] = f32_to_bf16(W1[k * H_DIM + col]);
      }
    }
}

// ---------------------------------------------------------------------------
// Segment start offsets (batch sorted; int32/int64 runtime detect).
// ---------------------------------------------------------------------------
__global__ void offsets_kernel(const void* __restrict__ batch, int* __restrict__ start,
                               int N, int G)
{
  int g = blockIdx.x * blockDim.x + threadIdx.x;
  if (g > G) return;
  const int* b32 = (const int*)batch;
  bool is64 = (b32[N - 1] != G - 1);
  int lo = 0, hi = N;
  while (lo < hi) {
    int mid = (lo + hi) >> 1;
    long long v = is64 ? ((const long long*)batch)[mid] : (long long)b32[mid];
    if (v < (long long)g) lo = mid + 1; else hi = mid;
  }
  start[g] = lo;
}

// convert one 8-f32 chunk to bf16 hi/lo and store to the LDS tile
__device__ __forceinline__ void convert_store(unsigned short (*xh)[HPAD],
                                              unsigned short (*xl)[HPAD],
                                              int row, int col8, float4 A, float4 B)
{
  float r0, r1, r2, r3, r4, r5, r6, r7;
  uint4 H, L;
  H.x = pack_hi2(A.x, A.y, r0, r1);  H.y = pack_hi2(A.z, A.w, r2, r3);
  H.z = pack_hi2(B.x, B.y, r4, r5);  H.w = pack_hi2(B.z, B.w, r6, r7);
  L.x = pack_lo2(r0, r1);  L.y = pack_lo2(r2, r3);
  L.z = pack_lo2(r4, r5);  L.w = pack_lo2(r6, r7);
  *reinterpret_cast<uint4*>(&xh[row][col8]) = H;
  *reinterpret_cast<uint4*>(&xl[row][col8]) = L;
}

// ---------------------------------------------------------------------------
// Fused single-pass, block per graph, 32-node tiles. R5 skeleton (no spill at
// the ~84-VGPR budget), with two LDS cuts:
//  - MFMA on bf16-hi ONLY (frag reads halved; R6-validated accuracy)
//  - pool: thread owns 2 dims x 16 rows, packed b32 reads of hi/lo pairs
//    (32 b32 vs 64 u16 insts), 2 named accumulators, 2 KB LDS reduce at end
// ---------------------------------------------------------------------------
__global__ __launch_bounds__(256, 3)
void fused_kernel(const float* __restrict__ x, const unsigned short* __restrict__ wfrag,
                  const float* __restrict__ b1, const float* __restrict__ W2,
                  const int* __restrict__ start, float* __restrict__ out, int N)
{
  __shared__ unsigned short xhi[TILE][HPAD];  // 16.9 KB
  __shared__ unsigned short xlo[TILE][HPAD];  // 16.9 KB
  __shared__ float part[4][TILE];             // per-wave logit partials
  __shared__ float redbuf[2][D_DIM];          // 2 KB, end-of-block reduce

  const int g = blockIdx.x;
  const int tid = threadIdx.x;
  const int s = start[g], e = start[g + 1];
  if (s >= e) { out[(size_t)g * D_DIM + tid] = 0.0f; return; }
  const int len = e - s;

  const int lane = tid & 63, w = tid >> 6;
  const int q = lane >> 4, c = lane & 15;
  const int srow = tid >> 5, scol8 = (tid & 31) * 8;   // staging coords
  const int halfsel = tid >> 7;                        // pool: row half (wave-uniform)
  const int dim2 = (tid & 127) * 2;                    // pool: 2 owned dims

  const bf16x8* wfv = (const bf16x8*)wfrag;

  float b1c0, b1c1, w2c0, w2c1;
  {
    int col0 = w * 32 + c, col1 = w * 32 + 16 + c;
    b1c0 = b1[col0]; b1c1 = b1[col1];
    w2c0 = W2[col0]; w2c1 = W2[col1];
  }

  float m_run = -INFINITY, Z = 0.0f;
  float pcA = 0.f, pcB = 0.f;                 // 2 pooled-dim accumulators
  const int nT = (len + TILE - 1) / TILE;

  // ---- prologue: stage tile 0 ----
  {
    const float4* g0 = reinterpret_cast<const float4*>(x + (size_t)min(s + srow,      N - 1) * D_DIM + scol8);
    const float4* g1 = reinterpret_cast<const float4*>(x + (size_t)min(s + srow +  8, N - 1) * D_DIM + scol8);
    const float4* g2 = reinterpret_cast<const float4*>(x + (size_t)min(s + srow + 16, N - 1) * D_DIM + scol8);
    const float4* g3 = reinterpret_cast<const float4*>(x + (size_t)min(s + srow + 24, N - 1) * D_DIM + scol8);
    convert_store(xhi, xlo, srow,      scol8, g0[0], g0[1]);
    convert_store(xhi, xlo, srow +  8, scol8, g1[0], g1[1]);
    convert_store(xhi, xlo, srow + 16, scol8, g2[0], g2[1]);
    convert_store(xhi, xlo, srow + 24, scol8, g3[0], g3[1]);
  }

  for (int ti = 0; ti < nT; ++ti) {
    const int t0 = ti * TILE;
    const int iend = min(TILE, len - t0);

    __syncthreads();   // LDS tile ti ready

    // ---- T14: issue next tile's loads into NAMED registers (R5 pattern) ----
    float4 pA0, pB0, pA1, pB1, pA2, pB2, pA3, pB3;
    {
      const int nb = s + t0 + TILE;
      const float4* g0 = reinterpret_cast<const float4*>(x + (size_t)min(nb + srow,      N - 1) * D_DIM + scol8);
      const float4* g1 = reinterpret_cast<const float4*>(x + (size_t)min(nb + srow +  8, N - 1) * D_DIM + scol8);
      const float4* g2 = reinterpret_cast<const float4*>(x + (size_t)min(nb + srow + 16, N - 1) * D_DIM + scol8);
      const float4* g3 = reinterpret_cast<const float4*>(x + (size_t)min(nb + srow + 24, N - 1) * D_DIM + scol8);
      pA0 = g0[0]; pB0 = g0[1];
      pA1 = g1[0]; pB1 = g1[1];
      pA2 = g2[0]; pB2 = g2[1];
      pA3 = g3[0]; pB3 = g3[1];
    }

    // ---- MFMA (hi only): h = x_tile @ W1[:, wave's 32 cols] ----
    f32x4 acc00 = {0.f, 0.f, 0.f, 0.f}, acc01 = {0.f, 0.f, 0.f, 0.f};
    f32x4 acc10 = {0.f, 0.f, 0.f, 0.f}, acc11 = {0.f, 0.f, 0.f, 0.f};
#pragma unroll
    for (int kt = 0; kt < 8; ++kt) {
      const int koff = kt * 32 + q * 8;
      bf16x8 ah0 = *reinterpret_cast<const bf16x8*>(&xhi[c][koff]);
      bf16x8 ah1 = *reinterpret_cast<const bf16x8*>(&xhi[16 + c][koff]);
      bf16x8 bf0 = wfv[(kt * 2 + 0) * 256 + tid];   // L2-resident
      bf16x8 bf1 = wfv[(kt * 2 + 1) * 256 + tid];
      acc00 = __builtin_amdgcn_mfma_f32_16x16x32_bf16(ah0, bf0, acc00, 0, 0, 0);
      acc01 = __builtin_amdgcn_mfma_f32_16x16x32_bf16(ah0, bf1, acc01, 0, 0, 0);
      acc10 = __builtin_amdgcn_mfma_f32_16x16x32_bf16(ah1, bf0, acc10, 0, 0, 0);
      acc11 = __builtin_amdgcn_mfma_f32_16x16x32_bf16(ah1, bf1, acc11, 0, 0, 0);
    }

    // ---- tanh + W2 dot; reduce across the 16 col-lanes -> part[w][i] ----
#pragma unroll
    for (int r = 0; r < 4; ++r) {
      float v = tanh_fast(acc00[r] + b1c0) * w2c0 + tanh_fast(acc01[r] + b1c1) * w2c1;
#pragma unroll
      for (int o = 1; o < 16; o <<= 1) v += __shfl_xor(v, o, 64);
      if (c == 0) part[w][q * 4 + r] = v;
    }
#pragma unroll
    for (int r = 0; r < 4; ++r) {
      float v = tanh_fast(acc10[r] + b1c0) * w2c0 + tanh_fast(acc11[r] + b1c1) * w2c1;
#pragma unroll
      for (int o = 1; o < 16; o <<= 1) v += __shfl_xor(v, o, 64);
      if (c == 0) part[w][16 + q * 4 + r] = v;
    }
    __syncthreads();   // part ready

    // ---- online softmax (every wave; lane i&31 owns e_i) + pool ----
    {
      const int i = lane & 31;
      float li = (i < iend) ? (part[0][i] + part[1][i] + part[2][i] + part[3][i])
                            : -INFINITY;
      float tmax = li;
#pragma unroll
      for (int o = 1; o < 32; o <<= 1) tmax = fmaxf(tmax, __shfl_xor(tmax, o, 64));
      float m_new = fmaxf(m_run, tmax);
      float ei = __expf(li - m_new);              // 0 for pad lanes
      float esum = ei;
#pragma unroll
      for (int o = 1; o < 32; o <<= 1) esum += __shfl_xor(esum, o, 64);
      float scale = __expf(m_run - m_new);        // first tile: exp(-inf)=0
      Z = Z * scale + esum;
      m_run = m_new;

      // ---- pool: thread owns dims {dim2, dim2+1}, rows halfsel*16+0..15 ----
      pcA *= scale; pcB *= scale;
#pragma unroll
      for (int ii = 0; ii < 16; ++ii) {
        const int row = halfsel * 16 + ii;
        float er = __shfl(ei, row, 64);           // e for this row (0 if pad)
        unsigned int hx = *reinterpret_cast<const unsigned int*>(&xhi[row][dim2]);
        unsigned int lx = *reinterpret_cast<const unsigned int*>(&xlo[row][dim2]);
        float x0 = __uint_as_float(hx << 16)         + __uint_as_float(lx << 16);
        float x1 = __uint_as_float(hx & 0xFFFF0000u) + __uint_as_float(lx & 0xFFFF0000u);
        pcA = fmaf(er, x0, pcA);
        pcB = fmaf(er, x1, pcB);
      }
    }
    __syncthreads();   // pool done; LDS free to overwrite

    // ---- writeback prefetched tile ti+1 (unconditional; dead on last tile) ----
    convert_store(xhi, xlo, srow,      scol8, pA0, pB0);
    convert_store(xhi, xlo, srow +  8, scol8, pA1, pB1);
    convert_store(xhi, xlo, srow + 16, scol8, pA2, pB2);
    convert_store(xhi, xlo, srow + 24, scol8, pA3, pB3);
  }

  // ---- cross-half reduce of pooled partials ----
  redbuf[halfsel][dim2]     = pcA;
  redbuf[halfsel][dim2 + 1] = pcB;
  __syncthreads();
  out[(size_t)g * D_DIM + tid] = (redbuf[0][tid] + redbuf[1][tid]) / Z;
}

// ---------------------------------------------------------------------------
extern "C" void kernel_launch(void* const* d_in, const int* in_sizes, int n_in,
                              void* d_out, int out_size, void* d_ws, size_t ws_size,
                              hipStream_t stream)
{
  const float* x     = (const float*)d_in[0];
  const void*  batch = d_in[1];
  const float* W1    = (const float*)d_in[2];
  const float* b1    = (const float*)d_in[3];
  const float* W2    = (const float*)d_in[4];
  // d_in[5] = b2: cancels exactly in the segment softmax -> unused.

  const int N = in_sizes[0] / D_DIM;     // 500000
  const int G = out_size / D_DIM;        // 4096

  unsigned short* wfrag = (unsigned short*)d_ws;              // 64 KB
  int* startA = (int*)((char*)d_ws + 16 * 256 * 8 * sizeof(unsigned short));
  float* out = (float*)d_out;

  setup_w1_kernel<<<1, 256, 0, stream>>>(W1, wfrag);
  offsets_kernel<<<(G + 1 + 255) / 256, 256, 0, stream>>>(batch, startA, N, G);
  fused_kernel<<<G, 256, 0, stream>>>(x, wfrag, b1, W2, startA, out, N);
}